// Round 1
// baseline (474.994 us; speedup 1.0000x reference)
//
#include <hip/hip_runtime.h>
#include <hip/hip_bf16.h>
#include <cfloat>

typedef __attribute__((ext_vector_type(8))) short bf16x8;
typedef __attribute__((ext_vector_type(4))) float f32x4;

#define M_DIM 8192
#define N_DIM 4096
#define K_DIM 4096

__device__ inline ushort f2bf(float f) {
    unsigned u = __float_as_uint(f);
    unsigned r = (u + 0x7FFFu + ((u >> 16) & 1u)) >> 16;
    return (ushort)r;
}

// ---------------- kernel 1: weight 4-bit group-128 quant-dequant -> bf16 ----------------
// one wave per group of 128; grid = 131072/4 groups
__global__ __launch_bounds__(256) void w_dequant(const float* __restrict__ w,
                                                 ushort* __restrict__ wq) {
    int g = blockIdx.x * 4 + (threadIdx.x >> 6);
    int lane = threadIdx.x & 63;
    const float* src = w + (size_t)g * 128;
    float2 v = *(const float2*)(src + lane * 2);
    float mn = fminf(v.x, v.y), mx = fmaxf(v.x, v.y);
#pragma unroll
    for (int s = 1; s < 64; s <<= 1) {
        mn = fminf(mn, __shfl_xor(mn, s));
        mx = fmaxf(mx, __shfl_xor(mx, s));
    }
    float scale = (mx - mn) / 15.0f;               // (qmax-qmin)=15, fp32 div like ref
    float zero  = -8.0f - rintf(mn / scale);       // rintf == jnp.round (RNE)
    float q0 = fminf(fmaxf(rintf(v.x / scale) + zero, -8.0f), 7.0f);
    float q1 = fminf(fmaxf(rintf(v.y / scale) + zero, -8.0f), 7.0f);
    ushort2 o;
    o.x = f2bf((q0 - zero) * scale);
    o.y = f2bf((q1 - zero) * scale);
    *(ushort2*)(wq + (size_t)g * 128 + lane * 2) = o;
}

// ---------------- kernel 2: per-row int8 act quant-dequant -> bf16 ----------------
// one 256-thread block per row of 4096
__global__ __launch_bounds__(256) void act_qdq(const float* __restrict__ x,
                                               ushort* __restrict__ xq) {
    __shared__ float smn[4], smx[4];
    int row = blockIdx.x;
    const float* xr = x + (size_t)row * K_DIM;
    ushort* xo = xq + (size_t)row * K_DIM;
    int t = threadIdx.x;
    float4 v[4];
    float mn = FLT_MAX, mx = -FLT_MAX;
#pragma unroll
    for (int i = 0; i < 4; i++) {
        v[i] = ((const float4*)xr)[t + i * 256];
        mn = fminf(mn, fminf(fminf(v[i].x, v[i].y), fminf(v[i].z, v[i].w)));
        mx = fmaxf(mx, fmaxf(fmaxf(v[i].x, v[i].y), fmaxf(v[i].z, v[i].w)));
    }
#pragma unroll
    for (int s = 1; s < 64; s <<= 1) {
        mn = fminf(mn, __shfl_xor(mn, s));
        mx = fmaxf(mx, __shfl_xor(mx, s));
    }
    int w = t >> 6;
    if ((t & 63) == 0) { smn[w] = mn; smx[w] = mx; }
    __syncthreads();
    mn = fminf(fminf(smn[0], smn[1]), fminf(smn[2], smn[3]));
    mx = fmaxf(fmaxf(smx[0], smx[1]), fmaxf(smx[2], smx[3]));
    float scale = (mx - mn) / 255.0f;              // (127-(-128)) = 255
    float zero  = -128.0f - rintf(mn / scale);
#pragma unroll
    for (int i = 0; i < 4; i++) {
        float e0 = v[i].x, e1 = v[i].y, e2 = v[i].z, e3 = v[i].w;
        ushort4 o;
        float q;
        q = fminf(fmaxf(rintf(e0 / scale) + zero, -128.0f), 127.0f); o.x = f2bf((q - zero) * scale);
        q = fminf(fmaxf(rintf(e1 / scale) + zero, -128.0f), 127.0f); o.y = f2bf((q - zero) * scale);
        q = fminf(fmaxf(rintf(e2 / scale) + zero, -128.0f), 127.0f); o.z = f2bf((q - zero) * scale);
        q = fminf(fmaxf(rintf(e3 / scale) + zero, -128.0f), 127.0f); o.w = f2bf((q - zero) * scale);
        ((ushort4*)xo)[t + i * 256] = o;
    }
}

// ---------------- kernel 3: bf16 GEMM, C[M,N] = A[M,K] * B[N,K]^T ----------------
// m97 structure: 128x128 tile, BK=32, 4 waves (2x2 of 64x64), global_load_lds(16B)
#define BM 128
#define BN 128
#define BK 32

__global__ __launch_bounds__(256) void gemm_bt(const ushort* __restrict__ A,
                                               const ushort* __restrict__ B,
                                               float* __restrict__ C) {
    __shared__ __align__(16) ushort Alds[BM][BK];
    __shared__ __align__(16) ushort Blds[BN][BK];

    const int nbx = N_DIM / BN;              // 32
    const int cpx = (M_DIM / BM) * nbx / 8;  // 256 blocks per XCD
    int bid = blockIdx.x;
    bid = (bid & 7) * cpx + (bid >> 3);      // bijective XCD swizzle (nwg%8==0)
    int mb = bid / nbx, nb = bid % nbx;
    size_t m0 = (size_t)mb * BM, n0 = (size_t)nb * BN;

    int t = threadIdx.x;
    int w = t >> 6, lane = t & 63;
    int wm = w >> 1, wn = w & 1;
    int lr = lane & 15;                 // fragment row
    int lk = (lane >> 4) << 3;          // fragment k-offset (0/8/16/24)

    int srow = lane >> 2;               // staging: row advance within wave chunk
    int scol = (lane & 3) << 3;         // staging: elem offset 0/8/16/24

    f32x4 acc[4][4] = {};

    const ushort* Ab = A + m0 * K_DIM;
    const ushort* Bb = B + n0 * K_DIM;

    for (int k0 = 0; k0 < K_DIM; k0 += BK) {
#pragma unroll
        for (int j = 0; j < 2; j++) {
            int row = j * 64 + w * 16 + srow;
            __builtin_amdgcn_global_load_lds(
                (const __attribute__((address_space(1))) unsigned int*)(Ab + (size_t)row * K_DIM + k0 + scol),
                (__attribute__((address_space(3))) unsigned int*)(&Alds[j * 64 + w * 16][0]),
                16, 0, 0);
        }
#pragma unroll
        for (int j = 0; j < 2; j++) {
            int row = j * 64 + w * 16 + srow;
            __builtin_amdgcn_global_load_lds(
                (const __attribute__((address_space(1))) unsigned int*)(Bb + (size_t)row * K_DIM + k0 + scol),
                (__attribute__((address_space(3))) unsigned int*)(&Blds[j * 64 + w * 16][0]),
                16, 0, 0);
        }
        __syncthreads();

        bf16x8 af[4], bf[4];
#pragma unroll
        for (int mi = 0; mi < 4; mi++)
            af[mi] = *(const bf16x8*)&Alds[wm * 64 + mi * 16 + lr][lk];
#pragma unroll
        for (int ni = 0; ni < 4; ni++)
            bf[ni] = *(const bf16x8*)&Blds[wn * 64 + ni * 16 + lr][lk];
#pragma unroll
        for (int mi = 0; mi < 4; mi++)
#pragma unroll
            for (int ni = 0; ni < 4; ni++)
                acc[mi][ni] = __builtin_amdgcn_mfma_f32_16x16x32_bf16(af[mi], bf[ni], acc[mi][ni], 0, 0, 0);
        __syncthreads();
    }

    // epilogue: C row = m-block + fq*4 + r (A operand), col = n-block + fr (B operand)
    int fq = lane >> 4;
#pragma unroll
    for (int mi = 0; mi < 4; mi++) {
#pragma unroll
        for (int ni = 0; ni < 4; ni++) {
#pragma unroll
            for (int r = 0; r < 4; r++) {
                size_t crow = m0 + wm * 64 + mi * 16 + fq * 4 + r;
                C[crow * N_DIM + n0 + wn * 64 + ni * 16 + lr] = acc[mi][ni][r];
            }
        }
    }
}

extern "C" void kernel_launch(void* const* d_in, const int* in_sizes, int n_in,
                              void* d_out, int out_size, void* d_ws, size_t ws_size,
                              hipStream_t stream) {
    const float* x = (const float*)d_in[0];
    const float* w = (const float*)d_in[1];
    float* out = (float*)d_out;

    ushort* wq = (ushort*)d_ws;                                        // 4096*4096*2 = 32 MiB
    ushort* xq = (ushort*)((char*)d_ws + (size_t)N_DIM * K_DIM * 2);   // 8192*4096*2 = 64 MiB

    hipLaunchKernelGGL(w_dequant, dim3((N_DIM * K_DIM / 128) / 4), dim3(256), 0, stream, w, wq);
    hipLaunchKernelGGL(act_qdq, dim3(M_DIM), dim3(256), 0, stream, x, xq);
    hipLaunchKernelGGL(gemm_bt, dim3((M_DIM / BM) * (N_DIM / BN)), dim3(256), 0, stream, xq, wq, out);
}

// Round 3
// 348.389 us; speedup vs baseline: 1.3634x; 1.3634x over previous
//
#include <hip/hip_runtime.h>
#include <hip/hip_bf16.h>
#include <cfloat>

typedef __attribute__((ext_vector_type(8))) short bf16x8;
typedef __attribute__((ext_vector_type(4))) float f32x4;

#define M_DIM 8192
#define N_DIM 4096
#define K_DIM 4096

__device__ inline ushort f2bf(float f) {
    unsigned u = __float_as_uint(f);
    unsigned r = (u + 0x7FFFu + ((u >> 16) & 1u)) >> 16;
    return (ushort)r;
}

// ---------------- kernel 1: weight 4-bit group-128 quant-dequant -> bf16 ----------------
__global__ __launch_bounds__(256) void w_dequant(const float* __restrict__ w,
                                                 ushort* __restrict__ wq) {
    int g = blockIdx.x * 4 + (threadIdx.x >> 6);
    int lane = threadIdx.x & 63;
    const float* src = w + (size_t)g * 128;
    float2 v = *(const float2*)(src + lane * 2);
    float mn = fminf(v.x, v.y), mx = fmaxf(v.x, v.y);
#pragma unroll
    for (int s = 1; s < 64; s <<= 1) {
        mn = fminf(mn, __shfl_xor(mn, s));
        mx = fmaxf(mx, __shfl_xor(mx, s));
    }
    float scale = (mx - mn) / 15.0f;
    float zero  = -8.0f - rintf(mn / scale);
    float q0 = fminf(fmaxf(rintf(v.x / scale) + zero, -8.0f), 7.0f);
    float q1 = fminf(fmaxf(rintf(v.y / scale) + zero, -8.0f), 7.0f);
    ushort2 o;
    o.x = f2bf((q0 - zero) * scale);
    o.y = f2bf((q1 - zero) * scale);
    *(ushort2*)(wq + (size_t)g * 128 + lane * 2) = o;
}

// ---------------- kernel 2: per-row int8 act quant-dequant -> bf16 ----------------
__global__ __launch_bounds__(256) void act_qdq(const float* __restrict__ x,
                                               ushort* __restrict__ xq) {
    __shared__ float smn[4], smx[4];
    int row = blockIdx.x;
    const float* xr = x + (size_t)row * K_DIM;
    ushort* xo = xq + (size_t)row * K_DIM;
    int t = threadIdx.x;
    float4 v[4];
    float mn = FLT_MAX, mx = -FLT_MAX;
#pragma unroll
    for (int i = 0; i < 4; i++) {
        v[i] = ((const float4*)xr)[t + i * 256];
        mn = fminf(mn, fminf(fminf(v[i].x, v[i].y), fminf(v[i].z, v[i].w)));
        mx = fmaxf(mx, fmaxf(fmaxf(v[i].x, v[i].y), fmaxf(v[i].z, v[i].w)));
    }
#pragma unroll
    for (int s = 1; s < 64; s <<= 1) {
        mn = fminf(mn, __shfl_xor(mn, s));
        mx = fmaxf(mx, __shfl_xor(mx, s));
    }
    int w = t >> 6;
    if ((t & 63) == 0) { smn[w] = mn; smx[w] = mx; }
    __syncthreads();
    mn = fminf(fminf(smn[0], smn[1]), fminf(smn[2], smn[3]));
    mx = fmaxf(fmaxf(smx[0], smx[1]), fmaxf(smx[2], smx[3]));
    float scale = (mx - mn) / 255.0f;
    float zero  = -128.0f - rintf(mn / scale);
#pragma unroll
    for (int i = 0; i < 4; i++) {
        float e0 = v[i].x, e1 = v[i].y, e2 = v[i].z, e3 = v[i].w;
        ushort4 o;
        float q;
        q = fminf(fmaxf(rintf(e0 / scale) + zero, -128.0f), 127.0f); o.x = f2bf((q - zero) * scale);
        q = fminf(fmaxf(rintf(e1 / scale) + zero, -128.0f), 127.0f); o.y = f2bf((q - zero) * scale);
        q = fminf(fmaxf(rintf(e2 / scale) + zero, -128.0f), 127.0f); o.z = f2bf((q - zero) * scale);
        q = fminf(fmaxf(rintf(e3 / scale) + zero, -128.0f), 127.0f); o.w = f2bf((q - zero) * scale);
        ((ushort4*)xo)[t + i * 256] = o;
    }
}

// ---------------- kernel 3: 256x256 8-phase bf16 GEMM, C[M,N] = A[M,K] * B[N,K]^T ----------------
// Race-free stage slots: half overwriting region R is ISSUED after R's last-read phase
// (closing barrier follows every wave's lgkmcnt(0)); counted vmcnt(4) at ph3/ph7
// guarantees the next-read tile has fully landed. st_16x32 swizzle both-sides.
#define BM 256
#define BN 256
#define BK 64
#define NT (K_DIM / BK)   /* 64 K-tiles */
#define HH(T, q) (4 * (T) + (q))

__global__ __launch_bounds__(512, 1) void gemm_bt8(const ushort* __restrict__ A,
                                                   const ushort* __restrict__ B,
                                                   float* __restrict__ C) {
    __shared__ __align__(16) ushort As[2][BM * BK];   // 2 x 32 KiB
    __shared__ __align__(16) ushort Bs[2][BN * BK];   // 2 x 32 KiB

    const int nbx = N_DIM / BN;                 // 16
    const int nwg = (M_DIM / BM) * nbx;         // 512 (%8==0)
    int bid = blockIdx.x;
    bid = (bid & 7) * (nwg / 8) + (bid >> 3);   // bijective XCD swizzle
    int mb = bid / nbx, nb = bid % nbx;
    size_t m0 = (size_t)mb * BM, n0 = (size_t)nb * BN;

    const int t = threadIdx.x;
    const int w = t >> 6, lane = t & 63;
    const int wm = w >> 2, wn = w & 3;          // 2 x 4 wave grid; per-wave out 128x64
    const int lr = lane & 15;
    const int lk = (lane >> 4) << 3;

    const ushort* Ab = A + m0 * K_DIM;
    const ushort* Bb = B + n0 * K_DIM;

    // stage half-tile h = 4T+q: q0=A rows 0-127, q1=A rows 128-255, q2=B rows 0-127, q3=B 128-255
    auto STAGE = [&](int h) {
        if (h < 0 || h >= NT * 4) return;
        int T = h >> 2, q = h & 3;
        int d = T & 1;
        ushort* reg = (q < 2) ? As[d] : Bs[d];
        const ushort* gbase = (q < 2) ? Ab : Bb;
        int rhalf = q & 1;
        int k0 = T * BK;
#pragma unroll
        for (int l = 0; l < 2; l++) {
            int base = rhalf * 16384 + (w * 2 + l) * 1024;  // wave-uniform LDS byte base
            int lb = base + lane * 16;                      // physical byte this lane's 16B lands at
            int lg = lb ^ (((lb >> 9) & 1) << 5);           // logical byte (swizzle is an involution)
            int r = lg >> 7;                                // row 0..255
            int c = (lg & 127) >> 1;                        // col element (multiple of 8)
            __builtin_amdgcn_global_load_lds(
                (const __attribute__((address_space(1))) unsigned int*)(gbase + (size_t)r * K_DIM + k0 + c),
                (__attribute__((address_space(3))) unsigned int*)((char*)reg + base),
                16, 0, 0);
        }
    };

    f32x4 acc[8][4] = {};
    bf16x8 afr[2][2], bfr[4][2];

#define PHASE(d, q, hA, hB, vm) do {                                              \
    if ((q) == 0) {                                                               \
        _Pragma("unroll") for (int ni = 0; ni < 4; ni++)                          \
        _Pragma("unroll") for (int kk = 0; kk < 2; kk++) {                        \
            int row = wn * 64 + ni * 16 + lr;                                     \
            int lg = row * 128 + (kk * 32 + lk) * 2;                              \
            int pb = lg ^ (((lg >> 9) & 1) << 5);                                 \
            bfr[ni][kk] = *(const bf16x8*)((const char*)Bs[d] + pb);              \
        }                                                                         \
    }                                                                             \
    _Pragma("unroll") for (int ii = 0; ii < 2; ii++)                              \
    _Pragma("unroll") for (int kk = 0; kk < 2; kk++) {                            \
        int row = wm * 128 + ((q) * 2 + ii) * 16 + lr;                            \
        int lg = row * 128 + (kk * 32 + lk) * 2;                                  \
        int pb = lg ^ (((lg >> 9) & 1) << 5);                                     \
        afr[ii][kk] = *(const bf16x8*)((const char*)As[d] + pb);                  \
    }                                                                             \
    STAGE(hA);                                                                    \
    STAGE(hB);                                                                    \
    __builtin_amdgcn_s_barrier();                                                 \
    asm volatile("s_waitcnt lgkmcnt(0)" ::: "memory");                            \
    __builtin_amdgcn_sched_barrier(0);                                            \
    __builtin_amdgcn_s_setprio(1);                                                \
    _Pragma("unroll") for (int ii = 0; ii < 2; ii++)                              \
    _Pragma("unroll") for (int ni = 0; ni < 4; ni++)                              \
    _Pragma("unroll") for (int kk = 0; kk < 2; kk++)                              \
        acc[(q) * 2 + ii][ni] = __builtin_amdgcn_mfma_f32_16x16x32_bf16(          \
            afr[ii][kk], bfr[ni][kk], acc[(q) * 2 + ii][ni], 0, 0, 0);            \
    __builtin_amdgcn_s_setprio(0);                                                \
    if ((vm) == 1) asm volatile("s_waitcnt vmcnt(4)" ::: "memory");               \
    if ((vm) == 2) asm volatile("s_waitcnt vmcnt(0)" ::: "memory");               \
    __builtin_amdgcn_s_barrier();                                                 \
  } while (0)

    // prologue: tile 0 (all 4 halves) + tile 1's B halves; drain so tile 0 is landed
    STAGE(HH(0, 0)); STAGE(HH(0, 1)); STAGE(HH(0, 2)); STAGE(HH(0, 3));
    STAGE(HH(1, 2)); STAGE(HH(1, 3));
    asm volatile("s_waitcnt vmcnt(4)" ::: "memory");
    __builtin_amdgcn_s_barrier();

    // main: iters 0..NT/2-2; iter i computes tiles 2i (buf0) and 2i+1 (buf1)
#pragma unroll 1
    for (int i = 0; i < NT / 2 - 1; i++) {
        int T2 = 2 * i;
        PHASE(0, 0, HH(T2 + 1, 0), -1,             0);
        PHASE(0, 1, HH(T2 + 1, 1), HH(T2 + 2, 2),  0);
        PHASE(0, 2, HH(T2 + 2, 3), -1,             0);
        PHASE(0, 3, -1, -1,                        1);   // tile 2i+1 fully landed
        PHASE(1, 0, HH(T2 + 2, 0), -1,             0);
        PHASE(1, 1, HH(T2 + 2, 1), HH(T2 + 3, 2),  0);
        PHASE(1, 2, HH(T2 + 3, 3), -1,             0);
        PHASE(1, 3, -1, -1,                        1);   // tile 2i+2 fully landed
    }

    // last iter (tiles NT-2, NT-1): stage NT-1's A halves, drain fully before ph4
    PHASE(0, 0, HH(NT - 1, 0), -1, 0);
    PHASE(0, 1, HH(NT - 1, 1), -1, 0);
    PHASE(0, 2, -1, -1, 0);
    PHASE(0, 3, -1, -1, 2);   // vmcnt(0): tile NT-1 landed
    PHASE(1, 0, -1, -1, 0);
    PHASE(1, 1, -1, -1, 0);
    PHASE(1, 2, -1, -1, 0);
    PHASE(1, 3, -1, -1, 0);
#undef PHASE

    // C write: row = m0 + wm*128 + mi*16 + (lane>>4)*4 + r ; col = n0 + wn*64 + ni*16 + lr
    int fq = lane >> 4;
#pragma unroll
    for (int mi = 0; mi < 8; mi++) {
#pragma unroll
        for (int ni = 0; ni < 4; ni++) {
#pragma unroll
            for (int r = 0; r < 4; r++) {
                size_t crow = m0 + wm * 128 + mi * 16 + fq * 4 + r;
                C[crow * N_DIM + n0 + wn * 64 + ni * 16 + lr] = acc[mi][ni][r];
            }
        }
    }
}

extern "C" void kernel_launch(void* const* d_in, const int* in_sizes, int n_in,
                              void* d_out, int out_size, void* d_ws, size_t ws_size,
                              hipStream_t stream) {
    const float* x = (const float*)d_in[0];
    const float* w = (const float*)d_in[1];
    float* out = (float*)d_out;

    ushort* wq = (ushort*)d_ws;                                        // 32 MiB
    ushort* xq = (ushort*)((char*)d_ws + (size_t)N_DIM * K_DIM * 2);   // 64 MiB

    hipLaunchKernelGGL(w_dequant, dim3((N_DIM * K_DIM / 128) / 4), dim3(256), 0, stream, w, wq);
    hipLaunchKernelGGL(act_qdq, dim3(M_DIM), dim3(256), 0, stream, x, xq);
    hipLaunchKernelGGL(gemm_bt8, dim3((M_DIM / BM) * (N_DIM / BN)), dim3(512), 0, stream, xq, wq, out);
}

// Round 4
// 330.484 us; speedup vs baseline: 1.4373x; 1.0542x over previous
//
#include <hip/hip_runtime.h>
#include <hip/hip_bf16.h>
#include <cfloat>

typedef __attribute__((ext_vector_type(8))) short bf16x8;
typedef __attribute__((ext_vector_type(4))) float f32x4;

#define M_DIM 8192
#define N_DIM 4096
#define K_DIM 4096

__device__ inline ushort f2bf(float f) {
    unsigned u = __float_as_uint(f);
    unsigned r = (u + 0x7FFFu + ((u >> 16) & 1u)) >> 16;
    return (ushort)r;
}

// swizzle: XOR 16B-slot index (bits 4-6) with row low bits (bits 7-9). Involution.
#define SWZ(x) ((x) ^ ((((x) >> 7) & 7) << 4))

// ---------------- kernel 1: weight 4-bit group-128 quant-dequant -> bf16 ----------------
__global__ __launch_bounds__(256) void w_dequant(const float* __restrict__ w,
                                                 ushort* __restrict__ wq) {
    int g = blockIdx.x * 4 + (threadIdx.x >> 6);
    int lane = threadIdx.x & 63;
    const float* src = w + (size_t)g * 128;
    float2 v = *(const float2*)(src + lane * 2);
    float mn = fminf(v.x, v.y), mx = fmaxf(v.x, v.y);
#pragma unroll
    for (int s = 1; s < 64; s <<= 1) {
        mn = fminf(mn, __shfl_xor(mn, s));
        mx = fmaxf(mx, __shfl_xor(mx, s));
    }
    float scale = (mx - mn) / 15.0f;
    float zero  = -8.0f - rintf(mn / scale);
    float q0 = fminf(fmaxf(rintf(v.x / scale) + zero, -8.0f), 7.0f);
    float q1 = fminf(fmaxf(rintf(v.y / scale) + zero, -8.0f), 7.0f);
    ushort2 o;
    o.x = f2bf((q0 - zero) * scale);
    o.y = f2bf((q1 - zero) * scale);
    *(ushort2*)(wq + (size_t)g * 128 + lane * 2) = o;
}

// ---------------- kernel 2: per-row int8 act quant-dequant -> bf16 ----------------
__global__ __launch_bounds__(256) void act_qdq(const float* __restrict__ x,
                                               ushort* __restrict__ xq) {
    __shared__ float smn[4], smx[4];
    int row = blockIdx.x;
    const float* xr = x + (size_t)row * K_DIM;
    ushort* xo = xq + (size_t)row * K_DIM;
    int t = threadIdx.x;
    float4 v[4];
    float mn = FLT_MAX, mx = -FLT_MAX;
#pragma unroll
    for (int i = 0; i < 4; i++) {
        v[i] = ((const float4*)xr)[t + i * 256];
        mn = fminf(mn, fminf(fminf(v[i].x, v[i].y), fminf(v[i].z, v[i].w)));
        mx = fmaxf(mx, fmaxf(fmaxf(v[i].x, v[i].y), fmaxf(v[i].z, v[i].w)));
    }
#pragma unroll
    for (int s = 1; s < 64; s <<= 1) {
        mn = fminf(mn, __shfl_xor(mn, s));
        mx = fmaxf(mx, __shfl_xor(mx, s));
    }
    int w = t >> 6;
    if ((t & 63) == 0) { smn[w] = mn; smx[w] = mx; }
    __syncthreads();
    mn = fminf(fminf(smn[0], smn[1]), fminf(smn[2], smn[3]));
    mx = fmaxf(fmaxf(smx[0], smx[1]), fmaxf(smx[2], smx[3]));
    float scale = (mx - mn) / 255.0f;
    float zero  = -128.0f - rintf(mn / scale);
#pragma unroll
    for (int i = 0; i < 4; i++) {
        float e0 = v[i].x, e1 = v[i].y, e2 = v[i].z, e3 = v[i].w;
        ushort4 o;
        float q;
        q = fminf(fmaxf(rintf(e0 / scale) + zero, -128.0f), 127.0f); o.x = f2bf((q - zero) * scale);
        q = fminf(fmaxf(rintf(e1 / scale) + zero, -128.0f), 127.0f); o.y = f2bf((q - zero) * scale);
        q = fminf(fmaxf(rintf(e2 / scale) + zero, -128.0f), 127.0f); o.z = f2bf((q - zero) * scale);
        q = fminf(fmaxf(rintf(e3 / scale) + zero, -128.0f), 127.0f); o.w = f2bf((q - zero) * scale);
        ((ushort4*)xo)[t + i * 256] = o;
    }
}

// ---------------- kernel 3: 256x256 8-phase bf16 GEMM, C[M,N] = A[M,K] * B[N,K]^T ----------------
// Race-free stage slots (issue-order + counted vmcnt(4) at ph3/ph7); row-xor LDS swizzle
// applied both-sides (inverse-swizzled global_load_lds source + swizzled ds_read).
#define BM 256
#define BN 256
#define BK 64
#define NT (K_DIM / BK)   /* 64 K-tiles */
#define HH(T, q) (4 * (T) + (q))

__global__ __launch_bounds__(512, 1) void gemm_bt8(const ushort* __restrict__ A,
                                                   const ushort* __restrict__ B,
                                                   float* __restrict__ C) {
    __shared__ __align__(16) ushort As[2][BM * BK];   // 2 x 32 KiB
    __shared__ __align__(16) ushort Bs[2][BN * BK];   // 2 x 32 KiB

    const int nbx = N_DIM / BN;                 // 16
    const int nwg = (M_DIM / BM) * nbx;         // 512 (%8==0)
    int bid = blockIdx.x;
    bid = (bid & 7) * (nwg / 8) + (bid >> 3);   // bijective XCD swizzle
    int mb = bid / nbx, nb = bid % nbx;
    size_t m0 = (size_t)mb * BM, n0 = (size_t)nb * BN;

    const int t = threadIdx.x;
    const int w = t >> 6, lane = t & 63;
    const int wm = w >> 2, wn = w & 3;          // 2 x 4 wave grid; per-wave out 128x64
    const int lr = lane & 15;
    const int lk = (lane >> 4) << 3;

    const ushort* Ab = A + m0 * K_DIM;
    const ushort* Bb = B + n0 * K_DIM;

    // stage half-tile h = 4T+q: q0=A rows 0-127, q1=A rows 128-255, q2=B rows 0-127, q3=B 128-255
    auto STAGE = [&](int h) {
        if (h < 0 || h >= NT * 4) return;
        int T = h >> 2, q = h & 3;
        int d = T & 1;
        ushort* reg = (q < 2) ? As[d] : Bs[d];
        const ushort* gbase = (q < 2) ? Ab : Bb;
        int rhalf = q & 1;
        int k0 = T * BK;
#pragma unroll
        for (int l = 0; l < 2; l++) {
            int base = rhalf * 16384 + (w * 2 + l) * 1024;  // wave-uniform LDS byte base
            int lb = base + lane * 16;                      // physical byte this lane's 16B lands at
            int lg = SWZ(lb);                               // logical byte (involution)
            int r = lg >> 7;                                // row 0..255
            int c = (lg & 127) >> 1;                        // col element (multiple of 8)
            __builtin_amdgcn_global_load_lds(
                (const __attribute__((address_space(1))) unsigned int*)(gbase + (size_t)r * K_DIM + k0 + c),
                (__attribute__((address_space(3))) unsigned int*)((char*)reg + base),
                16, 0, 0);
        }
    };

    f32x4 acc[8][4] = {};
    bf16x8 afr[2][2], bfr[4][2];

#define PHASE(d, q, hA, hB, vm) do {                                              \
    if ((q) == 0) {                                                               \
        _Pragma("unroll") for (int ni = 0; ni < 4; ni++)                          \
        _Pragma("unroll") for (int kk = 0; kk < 2; kk++) {                        \
            int row = wn * 64 + ni * 16 + lr;                                     \
            int lg = row * 128 + (kk * 32 + lk) * 2;                              \
            int pb = SWZ(lg);                                                     \
            bfr[ni][kk] = *(const bf16x8*)((const char*)Bs[d] + pb);              \
        }                                                                         \
    }                                                                             \
    _Pragma("unroll") for (int ii = 0; ii < 2; ii++)                              \
    _Pragma("unroll") for (int kk = 0; kk < 2; kk++) {                            \
        int row = wm * 128 + ((q) * 2 + ii) * 16 + lr;                            \
        int lg = row * 128 + (kk * 32 + lk) * 2;                                  \
        int pb = SWZ(lg);                                                         \
        afr[ii][kk] = *(const bf16x8*)((const char*)As[d] + pb);                  \
    }                                                                             \
    STAGE(hA);                                                                    \
    STAGE(hB);                                                                    \
    __builtin_amdgcn_s_barrier();                                                 \
    asm volatile("s_waitcnt lgkmcnt(0)" ::: "memory");                            \
    __builtin_amdgcn_sched_barrier(0);                                            \
    __builtin_amdgcn_s_setprio(1);                                                \
    _Pragma("unroll") for (int ii = 0; ii < 2; ii++)                              \
    _Pragma("unroll") for (int ni = 0; ni < 4; ni++)                              \
    _Pragma("unroll") for (int kk = 0; kk < 2; kk++)                              \
        acc[(q) * 2 + ii][ni] = __builtin_amdgcn_mfma_f32_16x16x32_bf16(          \
            afr[ii][kk], bfr[ni][kk], acc[(q) * 2 + ii][ni], 0, 0, 0);            \
    __builtin_amdgcn_s_setprio(0);                                                \
    if ((vm) == 1) asm volatile("s_waitcnt vmcnt(4)" ::: "memory");               \
    if ((vm) == 2) asm volatile("s_waitcnt vmcnt(0)" ::: "memory");               \
    __builtin_amdgcn_s_barrier();                                                 \
  } while (0)

    // prologue: tile 0 (all 4 halves) + tile 1's B halves; drain so tile 0 is landed
    STAGE(HH(0, 0)); STAGE(HH(0, 1)); STAGE(HH(0, 2)); STAGE(HH(0, 3));
    STAGE(HH(1, 2)); STAGE(HH(1, 3));
    asm volatile("s_waitcnt vmcnt(4)" ::: "memory");
    __builtin_amdgcn_s_barrier();

    // main: iters 0..NT/2-2; iter i computes tiles 2i (buf0) and 2i+1 (buf1)
#pragma unroll 1
    for (int i = 0; i < NT / 2 - 1; i++) {
        int T2 = 2 * i;
        PHASE(0, 0, HH(T2 + 1, 0), -1,             0);
        PHASE(0, 1, HH(T2 + 1, 1), HH(T2 + 2, 2),  0);
        PHASE(0, 2, HH(T2 + 2, 3), -1,             0);
        PHASE(0, 3, -1, -1,                        1);   // tile 2i+1 fully landed
        PHASE(1, 0, HH(T2 + 2, 0), -1,             0);
        PHASE(1, 1, HH(T2 + 2, 1), HH(T2 + 3, 2),  0);
        PHASE(1, 2, HH(T2 + 3, 3), -1,             0);
        PHASE(1, 3, -1, -1,                        1);   // tile 2i+2 fully landed
    }

    // last iter (tiles NT-2, NT-1): stage NT-1's A halves, drain fully before ph4
    PHASE(0, 0, HH(NT - 1, 0), -1, 0);
    PHASE(0, 1, HH(NT - 1, 1), -1, 0);
    PHASE(0, 2, -1, -1, 0);
    PHASE(0, 3, -1, -1, 2);   // vmcnt(0): tile NT-1 landed
    PHASE(1, 0, -1, -1, 0);
    PHASE(1, 1, -1, -1, 0);
    PHASE(1, 2, -1, -1, 0);
    PHASE(1, 3, -1, -1, 0);
#undef PHASE

    // C write: row = m0 + wm*128 + mi*16 + (lane>>4)*4 + r ; col = n0 + wn*64 + ni*16 + lr
    int fq = lane >> 4;
#pragma unroll
    for (int mi = 0; mi < 8; mi++) {
#pragma unroll
        for (int ni = 0; ni < 4; ni++) {
#pragma unroll
            for (int r = 0; r < 4; r++) {
                size_t crow = m0 + wm * 128 + mi * 16 + fq * 4 + r;
                C[crow * N_DIM + n0 + wn * 64 + ni * 16 + lr] = acc[mi][ni][r];
            }
        }
    }
}

extern "C" void kernel_launch(void* const* d_in, const int* in_sizes, int n_in,
                              void* d_out, int out_size, void* d_ws, size_t ws_size,
                              hipStream_t stream) {
    const float* x = (const float*)d_in[0];
    const float* w = (const float*)d_in[1];
    float* out = (float*)d_out;

    ushort* wq = (ushort*)d_ws;                                        // 32 MiB
    ushort* xq = (ushort*)((char*)d_ws + (size_t)N_DIM * K_DIM * 2);   // 64 MiB

    hipLaunchKernelGGL(w_dequant, dim3((N_DIM * K_DIM / 128) / 4), dim3(256), 0, stream, w, wq);
    hipLaunchKernelGGL(act_qdq, dim3(M_DIM), dim3(256), 0, stream, x, xq);
    hipLaunchKernelGGL(gemm_bt8, dim3((M_DIM / BM) * (N_DIM / BN)), dim3(512), 0, stream, xq, wq, out);
}

// Round 5
// 327.097 us; speedup vs baseline: 1.4522x; 1.0104x over previous
//
#include <hip/hip_runtime.h>
#include <hip/hip_bf16.h>
#include <cfloat>

typedef __attribute__((ext_vector_type(8))) short bf16x8;
typedef __attribute__((ext_vector_type(4))) float f32x4;

#define M_DIM 8192
#define N_DIM 4096
#define K_DIM 4096

__device__ inline ushort f2bf(float f) {
    unsigned u = __float_as_uint(f);
    unsigned r = (u + 0x7FFFu + ((u >> 16) & 1u)) >> 16;
    return (ushort)r;
}

// swizzle: XOR 16B-slot index (bits 4-6) with row low bits (bits 7-9). Involution.
#define SWZ(x) ((x) ^ ((((x) >> 7) & 7) << 4))

// ---------------- kernel 1: weight 4-bit group-128 quant-dequant -> bf16 ----------------
__global__ __launch_bounds__(256) void w_dequant(const float* __restrict__ w,
                                                 ushort* __restrict__ wq) {
    int g = blockIdx.x * 4 + (threadIdx.x >> 6);
    int lane = threadIdx.x & 63;
    const float* src = w + (size_t)g * 128;
    float2 v = *(const float2*)(src + lane * 2);
    float mn = fminf(v.x, v.y), mx = fmaxf(v.x, v.y);
#pragma unroll
    for (int s = 1; s < 64; s <<= 1) {
        mn = fminf(mn, __shfl_xor(mn, s));
        mx = fmaxf(mx, __shfl_xor(mx, s));
    }
    float scale = (mx - mn) / 15.0f;
    float zero  = -8.0f - rintf(mn / scale);
    float q0 = fminf(fmaxf(rintf(v.x / scale) + zero, -8.0f), 7.0f);
    float q1 = fminf(fmaxf(rintf(v.y / scale) + zero, -8.0f), 7.0f);
    ushort2 o;
    o.x = f2bf((q0 - zero) * scale);
    o.y = f2bf((q1 - zero) * scale);
    *(ushort2*)(wq + (size_t)g * 128 + lane * 2) = o;
}

// ---------------- kernel 2: per-row int8 act quant-dequant -> bf16 ----------------
__global__ __launch_bounds__(256) void act_qdq(const float* __restrict__ x,
                                               ushort* __restrict__ xq) {
    __shared__ float smn[4], smx[4];
    int row = blockIdx.x;
    const float* xr = x + (size_t)row * K_DIM;
    ushort* xo = xq + (size_t)row * K_DIM;
    int t = threadIdx.x;
    float4 v[4];
    float mn = FLT_MAX, mx = -FLT_MAX;
#pragma unroll
    for (int i = 0; i < 4; i++) {
        v[i] = ((const float4*)xr)[t + i * 256];
        mn = fminf(mn, fminf(fminf(v[i].x, v[i].y), fminf(v[i].z, v[i].w)));
        mx = fmaxf(mx, fmaxf(fmaxf(v[i].x, v[i].y), fmaxf(v[i].z, v[i].w)));
    }
#pragma unroll
    for (int s = 1; s < 64; s <<= 1) {
        mn = fminf(mn, __shfl_xor(mn, s));
        mx = fmaxf(mx, __shfl_xor(mx, s));
    }
    int w = t >> 6;
    if ((t & 63) == 0) { smn[w] = mn; smx[w] = mx; }
    __syncthreads();
    mn = fminf(fminf(smn[0], smn[1]), fminf(smn[2], smn[3]));
    mx = fmaxf(fmaxf(smx[0], smx[1]), fmaxf(smx[2], smx[3]));
    float scale = (mx - mn) / 255.0f;
    float zero  = -128.0f - rintf(mn / scale);
#pragma unroll
    for (int i = 0; i < 4; i++) {
        float e0 = v[i].x, e1 = v[i].y, e2 = v[i].z, e3 = v[i].w;
        ushort4 o;
        float q;
        q = fminf(fmaxf(rintf(e0 / scale) + zero, -128.0f), 127.0f); o.x = f2bf((q - zero) * scale);
        q = fminf(fmaxf(rintf(e1 / scale) + zero, -128.0f), 127.0f); o.y = f2bf((q - zero) * scale);
        q = fminf(fmaxf(rintf(e2 / scale) + zero, -128.0f), 127.0f); o.z = f2bf((q - zero) * scale);
        q = fminf(fmaxf(rintf(e3 / scale) + zero, -128.0f), 127.0f); o.w = f2bf((q - zero) * scale);
        ((ushort4*)xo)[t + i * 256] = o;
    }
}

// ---------------- kernel 3: 256x256 8-phase bf16 GEMM, C[M,N] = A[M,K] * B[N,K]^T ----------------
// Progressive-liveness schedule: phase q reads ONLY A-quarter q (rows q*64..+63) and (at q0)
// B; each quarter dies right after its phase. Uniform 2-quarter staging per phase with
// vmcnt(8) per phase -> every wait targets >=4-phase-old loads (stall-free prefetch, lead>=5).
#define BM 256
#define BN 256
#define BK 64
#define NT (K_DIM / BK)   /* 64 K-tiles */

__global__ __launch_bounds__(512, 1) void gemm_bt8(const ushort* __restrict__ A,
                                                   const ushort* __restrict__ B,
                                                   float* __restrict__ C) {
    __shared__ __align__(16) ushort As[2][BM * BK];   // 2 x 32 KiB, quarter q at byte q*8192
    __shared__ __align__(16) ushort Bs[2][BN * BK];

    const int nbx = N_DIM / BN;                 // 16
    const int nwg = (M_DIM / BM) * nbx;         // 512 (%8==0)
    int bid = blockIdx.x;
    bid = (bid & 7) * (nwg / 8) + (bid >> 3);   // bijective XCD swizzle
    int mb = bid / nbx, nb = bid % nbx;
    size_t m0 = (size_t)mb * BM, n0 = (size_t)nb * BN;

    const int t = threadIdx.x;
    const int w = t >> 6, lane = t & 63;
    const int wm = w >> 2, wn = w & 3;          // 2 x 4 wave grid
    const int lr = lane & 15;
    const int lk = (lane >> 4) << 3;

    const ushort* Ab = A + m0 * K_DIM;
    const ushort* Bb = B + n0 * K_DIM;

    // stage one 8KB quarter: qq 0-3 = A rows qq*64..+63, qq 4-7 = B rows (qq-4)*64..+63
    auto STAGE = [&](int T, int qq) {
        if (T >= NT) return;
        int d = T & 1;
        bool isA = qq < 4;
        int rq = isA ? qq : qq - 4;
        ushort* reg = isA ? As[d] : Bs[d];
        const ushort* gbase = isA ? Ab : Bb;
        int base = rq * 8192 + w * 1024;        // wave-uniform LDS byte base
        int lb = base + lane * 16;              // physical landing byte
        int lg = SWZ(lb);                       // logical byte (involution)
        int r = lg >> 7;                        // row 0..255
        int c = (lg & 127) >> 1;                // col element (multiple of 8)
        __builtin_amdgcn_global_load_lds(
            (const __attribute__((address_space(1))) unsigned int*)(gbase + (size_t)r * K_DIM + T * BK + c),
            (__attribute__((address_space(3))) unsigned int*)((char*)reg + base),
            16, 0, 0);
    };

    f32x4 acc[8][4] = {};
    bf16x8 afr[2][2], bfr[4][2];

#define PHASE(d, q, sT1, sq1, sT2, sq2, vm) do {                                  \
    if ((q) == 0) {                                                               \
        _Pragma("unroll") for (int ni = 0; ni < 4; ni++)                          \
        _Pragma("unroll") for (int kk = 0; kk < 2; kk++) {                        \
            int row = wn * 64 + ni * 16 + lr;                                     \
            int lg = row * 128 + (kk * 32 + lk) * 2;                              \
            int pb = SWZ(lg);                                                     \
            bfr[ni][kk] = *(const bf16x8*)((const char*)Bs[d] + pb);              \
        }                                                                         \
    }                                                                             \
    _Pragma("unroll") for (int ii = 0; ii < 2; ii++)                              \
    _Pragma("unroll") for (int kk = 0; kk < 2; kk++) {                            \
        int row = (q) * 64 + wm * 32 + ii * 16 + lr;                              \
        int lg = row * 128 + (kk * 32 + lk) * 2;                                  \
        int pb = SWZ(lg);                                                         \
        afr[ii][kk] = *(const bf16x8*)((const char*)As[d] + pb);                  \
    }                                                                             \
    STAGE(sT1, sq1);                                                              \
    STAGE(sT2, sq2);                                                              \
    __builtin_amdgcn_s_barrier();                                                 \
    asm volatile("s_waitcnt lgkmcnt(0)" ::: "memory");                            \
    __builtin_amdgcn_sched_barrier(0);                                            \
    __builtin_amdgcn_s_setprio(1);                                                \
    _Pragma("unroll") for (int ii = 0; ii < 2; ii++)                              \
    _Pragma("unroll") for (int ni = 0; ni < 4; ni++)                              \
    _Pragma("unroll") for (int kk = 0; kk < 2; kk++)                              \
        acc[(q) * 2 + ii][ni] = __builtin_amdgcn_mfma_f32_16x16x32_bf16(          \
            afr[ii][kk], bfr[ni][kk], acc[(q) * 2 + ii][ni], 0, 0, 0);            \
    __builtin_amdgcn_s_setprio(0);                                                \
    if ((vm) == 1) asm volatile("s_waitcnt vmcnt(8)" ::: "memory");               \
    if ((vm) == 2) asm volatile("s_waitcnt vmcnt(0)" ::: "memory");               \
    __builtin_amdgcn_s_barrier();                                                 \
  } while (0)

    // prologue: tile0 all 8 quarters, tile1 B quarters, tile1 A[0],A[1]; tile0 landed
    STAGE(0, 0); STAGE(0, 1); STAGE(0, 2); STAGE(0, 3);
    STAGE(0, 4); STAGE(0, 5); STAGE(0, 6); STAGE(0, 7);
    STAGE(1, 4); STAGE(1, 5); STAGE(1, 6); STAGE(1, 7);
    STAGE(1, 0); STAGE(1, 1);
    asm volatile("s_waitcnt vmcnt(6)" ::: "memory");
    __builtin_amdgcn_s_barrier();

    // main: iters 0..NT/2-2; iter i computes tiles 2i (buf0 ph0-3) and 2i+1 (buf1 ph4-7)
    // stage slots (all leads >=5 phases, all overwrites issue-after-death):
#pragma unroll 1
    for (int i = 0; i < NT / 2 - 1; i++) {
        int T0 = 2 * i;
        PHASE(0, 0, T0 + 1, 2, T0 + 1, 3, 1);
        PHASE(0, 1, T0 + 2, 4, T0 + 2, 5, 1);
        PHASE(0, 2, T0 + 2, 6, T0 + 2, 7, 1);
        PHASE(0, 3, T0 + 2, 0, T0 + 2, 1, 1);
        PHASE(1, 0, T0 + 2, 2, T0 + 2, 3, 1);
        PHASE(1, 1, T0 + 3, 4, T0 + 3, 5, 1);
        PHASE(1, 2, T0 + 3, 6, T0 + 3, 7, 1);
        PHASE(1, 3, T0 + 3, 0, T0 + 3, 1, 1);
    }

    // peeled last iter (tiles NT-2, NT-1): stage NT-1's A[2],A[3]; drain at ph3
    PHASE(0, 0, NT - 1, 2, NT - 1, 3, 1);
    PHASE(0, 1, NT, 0, NT, 0, 1);
    PHASE(0, 2, NT, 0, NT, 0, 1);
    PHASE(0, 3, NT, 0, NT, 0, 2);   // vmcnt(0): tile NT-1 (all >=4 phases old) landed
    PHASE(1, 0, NT, 0, NT, 0, 0);
    PHASE(1, 1, NT, 0, NT, 0, 0);
    PHASE(1, 2, NT, 0, NT, 0, 0);
    PHASE(1, 3, NT, 0, NT, 0, 0);
#undef PHASE

    // C write: acc[mi][ni], mi = q*2+ii -> row = m0 + (mi>>1)*64 + wm*32 + (mi&1)*16 + fq*4 + r
    int fq = lane >> 4;
#pragma unroll
    for (int mi = 0; mi < 8; mi++) {
#pragma unroll
        for (int ni = 0; ni < 4; ni++) {
#pragma unroll
            for (int r = 0; r < 4; r++) {
                size_t crow = m0 + (mi >> 1) * 64 + wm * 32 + (mi & 1) * 16 + fq * 4 + r;
                C[crow * N_DIM + n0 + wn * 64 + ni * 16 + lr] = acc[mi][ni][r];
            }
        }
    }
}

extern "C" void kernel_launch(void* const* d_in, const int* in_sizes, int n_in,
                              void* d_out, int out_size, void* d_ws, size_t ws_size,
                              hipStream_t stream) {
    const float* x = (const float*)d_in[0];
    const float* w = (const float*)d_in[1];
    float* out = (float*)d_out;

    ushort* wq = (ushort*)d_ws;                                        // 32 MiB
    ushort* xq = (ushort*)((char*)d_ws + (size_t)N_DIM * K_DIM * 2);   // 64 MiB

    hipLaunchKernelGGL(w_dequant, dim3((N_DIM * K_DIM / 128) / 4), dim3(256), 0, stream, w, wq);
    hipLaunchKernelGGL(act_qdq, dim3(M_DIM), dim3(256), 0, stream, x, xq);
    hipLaunchKernelGGL(gemm_bt8, dim3((M_DIM / BM) * (N_DIM / BN)), dim3(512), 0, stream, xq, wq, out);
}

// Round 7
// 324.293 us; speedup vs baseline: 1.4647x; 1.0086x over previous
//
#include <hip/hip_runtime.h>
#include <hip/hip_bf16.h>
#include <cfloat>

typedef __attribute__((ext_vector_type(8))) short bf16x8;
typedef __attribute__((ext_vector_type(4))) float f32x4;

#define M_DIM 8192
#define N_DIM 4096
#define K_DIM 4096

__device__ inline ushort f2bf(float f) {
    unsigned u = __float_as_uint(f);
    unsigned r = (u + 0x7FFFu + ((u >> 16) & 1u)) >> 16;
    return (ushort)r;
}

// swizzle: XOR 16B-slot index (bits 4-6) with row low bits (bits 7-9). Involution.
#define SWZ(x) ((x) ^ ((((x) >> 7) & 7) << 4))

// ---------------- kernel 1: weight 4-bit group-128 quant-dequant -> bf16 ----------------
__global__ __launch_bounds__(256) void w_dequant(const float* __restrict__ w,
                                                 ushort* __restrict__ wq) {
    int g = blockIdx.x * 4 + (threadIdx.x >> 6);
    int lane = threadIdx.x & 63;
    const float* src = w + (size_t)g * 128;
    float2 v = *(const float2*)(src + lane * 2);
    float mn = fminf(v.x, v.y), mx = fmaxf(v.x, v.y);
#pragma unroll
    for (int s = 1; s < 64; s <<= 1) {
        mn = fminf(mn, __shfl_xor(mn, s));
        mx = fmaxf(mx, __shfl_xor(mx, s));
    }
    float scale = (mx - mn) / 15.0f;
    float zero  = -8.0f - rintf(mn / scale);
    float q0 = fminf(fmaxf(rintf(v.x / scale) + zero, -8.0f), 7.0f);
    float q1 = fminf(fmaxf(rintf(v.y / scale) + zero, -8.0f), 7.0f);
    ushort2 o;
    o.x = f2bf((q0 - zero) * scale);
    o.y = f2bf((q1 - zero) * scale);
    *(ushort2*)(wq + (size_t)g * 128 + lane * 2) = o;
}

// ---------------- kernel 2: per-row int8 act quant-dequant -> bf16 ----------------
__global__ __launch_bounds__(256) void act_qdq(const float* __restrict__ x,
                                               ushort* __restrict__ xq) {
    __shared__ float smn[4], smx[4];
    int row = blockIdx.x;
    const float* xr = x + (size_t)row * K_DIM;
    ushort* xo = xq + (size_t)row * K_DIM;
    int t = threadIdx.x;
    float4 v[4];
    float mn = FLT_MAX, mx = -FLT_MAX;
#pragma unroll
    for (int i = 0; i < 4; i++) {
        v[i] = ((const float4*)xr)[t + i * 256];
        mn = fminf(mn, fminf(fminf(v[i].x, v[i].y), fminf(v[i].z, v[i].w)));
        mx = fmaxf(mx, fmaxf(fmaxf(v[i].x, v[i].y), fmaxf(v[i].z, v[i].w)));
    }
#pragma unroll
    for (int s = 1; s < 64; s <<= 1) {
        mn = fminf(mn, __shfl_xor(mn, s));
        mx = fmaxf(mx, __shfl_xor(mx, s));
    }
    int w = t >> 6;
    if ((t & 63) == 0) { smn[w] = mn; smx[w] = mx; }
    __syncthreads();
    mn = fminf(fminf(smn[0], smn[1]), fminf(smn[2], smn[3]));
    mx = fmaxf(fmaxf(smx[0], smx[1]), fmaxf(smx[2], smx[3]));
    float scale = (mx - mn) / 255.0f;
    float zero  = -128.0f - rintf(mn / scale);
#pragma unroll
    for (int i = 0; i < 4; i++) {
        float e0 = v[i].x, e1 = v[i].y, e2 = v[i].z, e3 = v[i].w;
        ushort4 o;
        float q;
        q = fminf(fmaxf(rintf(e0 / scale) + zero, -128.0f), 127.0f); o.x = f2bf((q - zero) * scale);
        q = fminf(fmaxf(rintf(e1 / scale) + zero, -128.0f), 127.0f); o.y = f2bf((q - zero) * scale);
        q = fminf(fmaxf(rintf(e2 / scale) + zero, -128.0f), 127.0f); o.z = f2bf((q - zero) * scale);
        q = fminf(fmaxf(rintf(e3 / scale) + zero, -128.0f), 127.0f); o.w = f2bf((q - zero) * scale);
        ((ushort4*)xo)[t + i * 256] = o;
    }
}

// ---------------- kernel 3: 256x256 bf16 GEMM, register-pipelined 8-phase ----------------
// Phase = [MFMA(afr[SA], bfr[SB])] [pre-read next A-quarter into afr[SN], B at qn==0 into
// bfr[dn]] [2 quarter-stages] [lgkmcnt(0)] [vmcnt(6)] [barrier].
// A frag sets alternate per phase; B frag sets indexed by BUFFER parity (persist 4 phases).
// Peeled tail drains with vmcnt(2)/vmcnt(0) since stages are guarded out there.
#define BM 256
#define BN 256
#define BK 64
#define NT (K_DIM / BK)   /* 64 K-tiles */

__global__ __launch_bounds__(512, 1) void gemm_bt8(const ushort* __restrict__ A,
                                                   const ushort* __restrict__ B,
                                                   float* __restrict__ C) {
    __shared__ __align__(16) ushort As[2][BM * BK];   // quarter q at byte q*8192
    __shared__ __align__(16) ushort Bs[2][BN * BK];

    const int nbx = N_DIM / BN;                 // 16
    const int nwg = (M_DIM / BM) * nbx;         // 512 (%8==0)
    int bid = blockIdx.x;
    bid = (bid & 7) * (nwg / 8) + (bid >> 3);   // bijective XCD swizzle
    int mb = bid / nbx, nb = bid % nbx;
    size_t m0 = (size_t)mb * BM, n0 = (size_t)nb * BN;

    const int t = threadIdx.x;
    const int w = t >> 6, lane = t & 63;
    const int wm = w >> 2, wn = w & 3;          // 2 x 4 wave grid
    const int lr = lane & 15;
    const int lk = (lane >> 4) << 3;

    const ushort* Ab = A + m0 * K_DIM;
    const ushort* Bb = B + n0 * K_DIM;

    // stage one 8KB quarter: qq 0-3 = A rows qq*64..+63, qq 4-7 = B rows (qq-4)*64..+63
    auto STAGE = [&](int T, int qq) {
        if (T >= NT) return;
        int d = T & 1;
        bool isA = qq < 4;
        int rq = isA ? qq : qq - 4;
        ushort* reg = isA ? As[d] : Bs[d];
        const ushort* gbase = isA ? Ab : Bb;
        int base = rq * 8192 + w * 1024;        // wave-uniform LDS byte base
        int lb = base + lane * 16;              // physical landing byte
        int lg = SWZ(lb);                       // logical byte (involution)
        int r = lg >> 7;                        // row 0..255
        int c = (lg & 127) >> 1;                // col element (multiple of 8)
        __builtin_amdgcn_global_load_lds(
            (const __attribute__((address_space(1))) unsigned int*)(gbase + (size_t)r * K_DIM + T * BK + c),
            (__attribute__((address_space(3))) unsigned int*)((char*)reg + base),
            16, 0, 0);
    };

    f32x4 acc[8][4] = {};
    bf16x8 afr[2][2][2];   // [phase-alt set][ii][kk]
    bf16x8 bfr[2][4][2];   // [BUFFER parity][ni][kk]

#define LOADA(S, d, q) do {                                                       \
    _Pragma("unroll") for (int ii = 0; ii < 2; ii++)                              \
    _Pragma("unroll") for (int kk = 0; kk < 2; kk++) {                            \
        int row = (q) * 64 + wm * 32 + ii * 16 + lr;                              \
        int lg = row * 128 + (kk * 32 + lk) * 2;                                  \
        afr[S][ii][kk] = *(const bf16x8*)((const char*)As[d] + SWZ(lg));          \
    } } while (0)
#define LOADB(S, d) do {                                                          \
    _Pragma("unroll") for (int ni = 0; ni < 4; ni++)                              \
    _Pragma("unroll") for (int kk = 0; kk < 2; kk++) {                            \
        int row = wn * 64 + ni * 16 + lr;                                         \
        int lg = row * 128 + (kk * 32 + lk) * 2;                                  \
        bfr[S][ni][kk] = *(const bf16x8*)((const char*)Bs[d] + SWZ(lg));          \
    } } while (0)

    // PHASE: MFMA quadrant q (A set SA, B set SB); pre-read A-quarter (dn,qn) into afr[SN],
    // B (all 4 n-frags) into bfr[dn] when qn==0; stage 2 quarters; wait; barrier.
    // vm: 0=vmcnt(6), 1=vmcnt(2), 2=vmcnt(0), 3=none
#define PHASE(q, SA, SB, SN, dn, qn, sT1, sq1, sT2, sq2, vm) do {                 \
    __builtin_amdgcn_s_setprio(1);                                                \
    _Pragma("unroll") for (int kk = 0; kk < 2; kk++)                              \
    _Pragma("unroll") for (int ii = 0; ii < 2; ii++)                              \
    _Pragma("unroll") for (int ni = 0; ni < 4; ni++)                              \
        acc[(q) * 2 + ii][ni] = __builtin_amdgcn_mfma_f32_16x16x32_bf16(          \
            afr[SA][ii][kk], bfr[SB][ni][kk], acc[(q) * 2 + ii][ni], 0, 0, 0);    \
    __builtin_amdgcn_s_setprio(0);                                                \
    if ((qn) == 0) LOADB(dn, dn);                                                 \
    LOADA(SN, dn, qn);                                                            \
    STAGE(sT1, sq1);                                                              \
    STAGE(sT2, sq2);                                                              \
    asm volatile("s_waitcnt lgkmcnt(0)" ::: "memory");                            \
    if ((vm) == 0) asm volatile("s_waitcnt vmcnt(6)" ::: "memory");               \
    if ((vm) == 1) asm volatile("s_waitcnt vmcnt(2)" ::: "memory");               \
    if ((vm) == 2) asm volatile("s_waitcnt vmcnt(0)" ::: "memory");               \
    __builtin_amdgcn_s_barrier();                                                 \
    __builtin_amdgcn_sched_barrier(0);                                            \
  } while (0)

    // prologue: tile0 all 8 quarters, tile1 B quarters, tile1 A0,A1; drain tile0; preload set0
    STAGE(0, 0); STAGE(0, 1); STAGE(0, 2); STAGE(0, 3);
    STAGE(0, 4); STAGE(0, 5); STAGE(0, 6); STAGE(0, 7);
    STAGE(1, 4); STAGE(1, 5); STAGE(1, 6); STAGE(1, 7);
    STAGE(1, 0); STAGE(1, 1);
    asm volatile("s_waitcnt vmcnt(6)" ::: "memory");
    __builtin_amdgcn_s_barrier();
    LOADB(0, 0);
    LOADA(0, 0, 0);
    asm volatile("s_waitcnt lgkmcnt(0)" ::: "memory");
    __builtin_amdgcn_sched_barrier(0);

    // main: iters 0..NT/2-2; iter i computes tiles 2i (buf0, ph0-3) and 2i+1 (buf1, ph4-7)
#pragma unroll 1
    for (int i = 0; i < NT / 2 - 1; i++) {
        int T0 = 2 * i;
        PHASE(0, 0, 0, 1, 0, 1, T0 + 1, 2, T0 + 1, 3, 0);
        PHASE(1, 1, 0, 0, 0, 2, T0 + 2, 4, T0 + 2, 5, 0);
        PHASE(2, 0, 0, 1, 0, 3, T0 + 2, 6, T0 + 2, 7, 0);
        PHASE(3, 1, 0, 0, 1, 0, T0 + 2, 0, T0 + 2, 1, 0);
        PHASE(0, 0, 1, 1, 1, 1, T0 + 2, 2, T0 + 2, 3, 0);
        PHASE(1, 1, 1, 0, 1, 2, T0 + 3, 4, T0 + 3, 5, 0);
        PHASE(2, 0, 1, 1, 1, 3, T0 + 3, 6, T0 + 3, 7, 0);
        PHASE(3, 1, 1, 0, 0, 0, T0 + 3, 0, T0 + 3, 1, 0);
    }

    // peeled last iter (tiles NT-2 buf0, NT-1 buf1): only NT-1's A-q2,q3 remain to stage;
    // stages guarded out afterwards, so drain explicitly (vmcnt(2) then vmcnt(0)).
    PHASE(0, 0, 0, 1, 0, 1, NT - 1, 2, NT - 1, 3, 0);
    PHASE(1, 1, 0, 0, 0, 2, NT, 0, NT, 0, 1);
    PHASE(2, 0, 0, 1, 0, 3, NT, 0, NT, 0, 2);
    PHASE(3, 1, 0, 0, 1, 0, NT, 0, NT, 0, 3);
    PHASE(0, 0, 1, 1, 1, 1, NT, 0, NT, 0, 3);
    PHASE(1, 1, 1, 0, 1, 2, NT, 0, NT, 0, 3);
    PHASE(2, 0, 1, 1, 1, 3, NT, 0, NT, 0, 3);
    PHASE(3, 1, 1, 0, 0, 0, NT, 0, NT, 0, 3);
#undef PHASE
#undef LOADA
#undef LOADB

    // C write: acc[mi][ni], mi = q*2+ii -> row = m0 + (mi>>1)*64 + wm*32 + (mi&1)*16 + fq*4 + r
    int fq = lane >> 4;
#pragma unroll
    for (int mi = 0; mi < 8; mi++) {
#pragma unroll
        for (int ni = 0; ni < 4; ni++) {
#pragma unroll
            for (int r = 0; r < 4; r++) {
                size_t crow = m0 + (mi >> 1) * 64 + wm * 32 + (mi & 1) * 16 + fq * 4 + r;
                C[crow * N_DIM + n0 + wn * 64 + ni * 16 + lr] = acc[mi][ni][r];
            }
        }
    }
}

extern "C" void kernel_launch(void* const* d_in, const int* in_sizes, int n_in,
                              void* d_out, int out_size, void* d_ws, size_t ws_size,
                              hipStream_t stream) {
    const float* x = (const float*)d_in[0];
    const float* w = (const float*)d_in[1];
    float* out = (float*)d_out;

    ushort* wq = (ushort*)d_ws;                                        // 32 MiB
    ushort* xq = (ushort*)((char*)d_ws + (size_t)N_DIM * K_DIM * 2);   // 64 MiB

    hipLaunchKernelGGL(w_dequant, dim3((N_DIM * K_DIM / 128) / 4), dim3(256), 0, stream, w, wq);
    hipLaunchKernelGGL(act_qdq, dim3(M_DIM), dim3(256), 0, stream, x, xq);
    hipLaunchKernelGGL(gemm_bt8, dim3((M_DIM / BM) * (N_DIM / BN)), dim3(512), 0, stream, xq, wq, out);
}